// Round 7
// baseline (112.941 us; speedup 1.0000x reference)
//
#include <hip/hip_runtime.h>

// Lovasz-Softmax, sort-free (bucket-quantized histogram + Jaccard scan).
// v6: 2 launches = zero + fused(hist|merge|ticket|scan|finalize).
// Fusion protocol (NO device fences -- v4's per-block __threadfence was a 3x
// regression from L2-writeback drains x912 blocks):
//   merge via device-scope atomicAdd (executes at the shared coherence point,
//   bypassing XCD-local L2) -> __syncthreads (compiler emits s_waitcnt
//   vmcnt(0) before s_barrier => merges globally performed) -> relaxed ticket
//   atomic. Last block per class observes ticket==NCHUNK-1 => all merges
//   happened-before; it re-reads the histogram with AGENT-scope atomic loads
//   (stale-cache bypass; bit-exact-verified in v4) and scans.
// Carried from v5: NB=1024, PIXPB=8192, class-fast grid (label L2 sharing,
// contention-free merge), u64-paired merge atomics.

#define NCLS   19
#define FHW    393216            // 4*256*384
#define NPIX   786432            // 2*FHW
#define NB     1024              // buckets per class (2^10) -> 4 KB LDS
#define PIXPB  8192              // pixels per hist block
#define NCHUNK (NPIX / PIXPB)    // 96 (48 per batch; no batch straddle)
#define BPT    (NB / 256)        // 4 buckets per scan thread

#define GH_WORDS  (NCLS * NB)    // 19456 packed hist words (~76 KB)
#define TOT_WORDS (GH_WORDS + NCLS + 4)   // + tick[19] + acc[4]

__device__ __forceinline__ void accum_one(unsigned int* h, float p, int lab, int c) {
    const bool fg = (lab == c);
    const float e = fg ? (1.0f - p) : p;             // e in [0,1]
    unsigned int bits = __float_as_uint(1.0f + e);   // [0x3F800000, 0x40000000]
    unsigned int bkt = (bits - 0x3F800000u) >> 13;   // 10-bit bucket (mantissa-linear)
    bkt = min(bkt, (unsigned int)(NB - 1));          // e == 1.0 exactly
    atomicAdd(&h[bkt], 1u + ((unsigned int)fg << 20)); // packed: cnt | fg<<20
}

__global__ __launch_bounds__(256) void zero_kernel(unsigned int* __restrict__ ws) {
    const int i = blockIdx.x * 256 + threadIdx.x;
    if (i < TOT_WORDS) ws[i] = 0u;                   // gH | tick | acc
}

__global__ __launch_bounds__(256) void fused_kernel(
        const float* __restrict__ input, const int* __restrict__ target,
        unsigned int* __restrict__ gH, float* __restrict__ out) {
    __shared__ unsigned int h[NB];                   // 4 KB
    const int tid = threadIdx.x;
    const int c = blockIdx.x;                        // class-fast: neighbors share labels,
    const int chunk = blockIdx.y;                    // merge to different histograms
    unsigned int* __restrict__ tick = gH + GH_WORDS;       // [NCLS]
    unsigned int* __restrict__ acc  = tick + NCLS;         // sum(f32), cnt, ticket

    #pragma unroll
    for (int i = tid; i < NB; i += 256) h[i] = 0u;
    __syncthreads();

    // ---------------- histogram phase (v5's proven load path) ----------------
    const int pix0 = chunk * PIXPB;
    const int b = pix0 / FHW;
    const int fhw0 = pix0 % FHW;
    const float4* __restrict__ p4 =
        (const float4*)(input + ((long long)(b * NCLS + c)) * FHW + fhw0);
    const int4* __restrict__ l4 = (const int4*)(target + pix0);

    #pragma unroll
    for (int i = tid; i < PIXPB / 4; i += 256) {     // 8 fully-unrolled iters
        float4 p = p4[i];
        int4 l = l4[i];
        accum_one(h, p.x, l.x, c);
        accum_one(h, p.y, l.y, c);
        accum_one(h, p.z, l.z, c);
        accum_one(h, p.w, l.w, c);
    }
    __syncthreads();

    // ---------------- merge phase: u64-paired device atomics ----------------
    unsigned int* __restrict__ g = gH + c * NB;
    unsigned long long* __restrict__ g64 = (unsigned long long*)g;
    #pragma unroll
    for (int i = tid; i < NB / 2; i += 256) {        // 2 iters/thread
        const unsigned long long v =
            (unsigned long long)h[2 * i] |
            ((unsigned long long)h[2 * i + 1] << 32);
        if (v) atomicAdd(&g64[i], v);
    }
    __syncthreads();                                 // drains vmcnt(0) -> merges performed

    __shared__ unsigned int sdone;
    if (tid == 0) {
        asm volatile("s_waitcnt vmcnt(0)" ::: "memory");   // belt & braces, ~free
        sdone = atomicAdd(&tick[c], 1u);             // relaxed ticket, no fence
    }
    __syncthreads();
    if (sdone != NCHUNK - 1) return;                 // not last for this class

    // ---------------- scan phase (last block of class c) ----------------
    unsigned int w[BPT];
    const int base = NB - BPT * (tid + 1);           // thread 0 = top buckets
    unsigned int sumN = 0, sumG = 0;
    #pragma unroll
    for (int j = 0; j < BPT; ++j) {
        w[j] = __hip_atomic_load(&g[base + j], __ATOMIC_RELAXED,
                                 __HIP_MEMORY_SCOPE_AGENT);   // stale-cache bypass
        sumN += w[j] & 0xFFFFFu;
        sumG += w[j] >> 20;
    }

    __shared__ unsigned long long sd[256];
    const unsigned long long mine = ((unsigned long long)sumG << 32) | sumN;
    sd[tid] = mine;
    __syncthreads();
    for (int off = 1; off < 256; off <<= 1) {
        unsigned long long add = (tid >= off) ? sd[tid - off] : 0ull;
        __syncthreads();
        sd[tid] += add;
        __syncthreads();
    }
    const unsigned long long incl = sd[tid];
    const unsigned long long tot = sd[255];
    const unsigned long long exc = incl - mine;      // fields don't borrow
    const unsigned int G = (unsigned int)(tot >> 32);

    float accv = 0.0f;
    if (G != 0u) {
        const float Gf = (float)G;
        unsigned int r = (unsigned int)exc;
        unsigned int cf = (unsigned int)(exc >> 32);
        float Jprev = __fdividef((float)r, Gf + (float)r - (float)cf);
        #pragma unroll
        for (int j = BPT - 1; j >= 0; --j) {         // descending error order
            const unsigned int nb = w[j] & 0xFFFFFu;
            const unsigned int gb = w[j] >> 20;
            r += nb; cf += gb;
            if (nb) {
                const float Jnew = __fdividef((float)r, Gf + (float)r - (float)cf);
                const float center = ((float)(base + j) + 0.5f) * (1.0f / (float)NB);
                accv += center * (Jnew - Jprev);
                Jprev = Jnew;
            }
        }
    }

    __shared__ float sf[256];
    sf[tid] = accv;
    __syncthreads();
    for (int off = 128; off > 0; off >>= 1) {
        if (tid < off) sf[tid] += sf[tid + off];
        __syncthreads();
    }
    if (tid == 0) {
        if (G != 0u) {
            atomicAdd((float*)&acc[0], sf[0]);       // class-loss sum
            atomicAdd(&acc[1], 1u);                  // present-class count
        }
        asm volatile("s_waitcnt vmcnt(0)" ::: "memory");   // acc adds performed
        const unsigned int t = atomicAdd(&acc[2], 1u);     // global class ticket
        if (t == NCLS - 1) {                         // last class finalizes
            const float s = atomicAdd((float*)&acc[0], 0.0f);   // coherent read
            const unsigned int k = atomicAdd(&acc[1], 0u);
            out[0] = s / fmaxf((float)k, 1.0f);
        }
    }
}

extern "C" void kernel_launch(void* const* d_in, const int* in_sizes, int n_in,
                              void* d_out, int out_size, void* d_ws, size_t ws_size,
                              hipStream_t stream) {
    const float* input = (const float*)d_in[0];
    const int* target = (const int*)d_in[1];
    float* out = (float*)d_out;

    unsigned int* ws = (unsigned int*)d_ws;          // gH | tick | acc

    zero_kernel<<<(TOT_WORDS + 255) / 256, 256, 0, stream>>>(ws);
    fused_kernel<<<dim3(NCLS, NCHUNK), 256, 0, stream>>>(input, target, ws, out);
}

// Round 8
// 99.204 us; speedup vs baseline: 1.1385x; 1.1385x over previous
//
#include <hip/hip_runtime.h>

// Lovasz-Softmax, sort-free (bucket-quantized histogram + Jaccard scan).
// v7: v5's 3-launch structure (v6 fusion was +11.5us, reverted) with a
// latency-targeted hist loop. v6's profile finally exposed the big kernel:
// 41us, 1.2 TB/s, VALU 7%, VGPR 16 -> only ~2 loads in flight per thread;
// the kernel is load-LATENCY bound (input is L3-resident), not BW/VALU/LDS
// bound. Fix: 4-way explicit load batching (8 independent 16B loads issued
// before any use -> ~8 in flight). NB=512 (halfwidth 9.8e-4 << 1.77e-2)
// halves LDS zero + merge tail. Carried: class-fast grid, u64-paired merge,
// ticket-fused finalize in scan.

#define NCLS   19
#define FHW    393216            // 4*256*384
#define NPIX   786432            // 2*FHW
#define NB     512               // buckets per class (2^9) -> 2 KB LDS
#define PIXPB  8192              // pixels per hist block
#define NCHUNK (NPIX / PIXPB)    // 96 (48 per batch; no batch straddle)
#define BPT    (NB / 256)        // 2 buckets per scan thread

#define GH_WORDS  (NCLS * NB)    // 9728 packed hist words (~38 KB)
#define TOT_WORDS (GH_WORDS + 4) // + acc[4] = sum(f32), cnt, ticket

__device__ __forceinline__ void accum_one(unsigned int* h, float p, int lab, int c) {
    const bool fg = (lab == c);
    const float e = fg ? (1.0f - p) : p;             // e in [0,1]
    unsigned int bits = __float_as_uint(1.0f + e);   // [0x3F800000, 0x40000000]
    unsigned int bkt = (bits - 0x3F800000u) >> 14;   // 9-bit bucket (mantissa-linear)
    bkt = min(bkt, (unsigned int)(NB - 1));          // e == 1.0 exactly
    atomicAdd(&h[bkt], 1u + ((unsigned int)fg << 20)); // packed: cnt | fg<<20
}

__global__ __launch_bounds__(256) void zero_kernel(unsigned int* __restrict__ ws) {
    const int i = blockIdx.x * 256 + threadIdx.x;
    if (i < TOT_WORDS) ws[i] = 0u;                   // gH | acc
}

__global__ __launch_bounds__(256) void hist_kernel(
        const float* __restrict__ input, const int* __restrict__ target,
        unsigned int* __restrict__ gH) {
    __shared__ unsigned int h[NB];                   // 2 KB
    const int tid = threadIdx.x;
    const int c = blockIdx.x;                        // class-fast: neighbors share labels,
    const int chunk = blockIdx.y;                    // merge to different histograms

    #pragma unroll
    for (int i = tid; i < NB; i += 256) h[i] = 0u;
    __syncthreads();

    const int pix0 = chunk * PIXPB;
    const int b = pix0 / FHW;
    const int fhw0 = pix0 % FHW;
    const float4* __restrict__ p4 =
        (const float4*)(input + ((long long)(b * NCLS + c)) * FHW + fhw0);
    const int4* __restrict__ l4 = (const int4*)(target + pix0);

    // 4-way batched loads: 8 independent 16B requests in flight per thread
    // (streams 4 KB apart -> distinct cache lines/channels), then consume.
    #pragma unroll
    for (int i = tid; i < PIXPB / 4; i += 1024) {    // 2 iters/thread
        const float4 pa = p4[i];
        const float4 pb = p4[i + 256];
        const float4 pc = p4[i + 512];
        const float4 pd = p4[i + 768];
        const int4  la = l4[i];
        const int4  lb = l4[i + 256];
        const int4  lc = l4[i + 512];
        const int4  ld = l4[i + 768];
        accum_one(h, pa.x, la.x, c); accum_one(h, pa.y, la.y, c);
        accum_one(h, pa.z, la.z, c); accum_one(h, pa.w, la.w, c);
        accum_one(h, pb.x, lb.x, c); accum_one(h, pb.y, lb.y, c);
        accum_one(h, pb.z, lb.z, c); accum_one(h, pb.w, lb.w, c);
        accum_one(h, pc.x, lc.x, c); accum_one(h, pc.y, lc.y, c);
        accum_one(h, pc.z, lc.z, c); accum_one(h, pc.w, lc.w, c);
        accum_one(h, pd.x, ld.x, c); accum_one(h, pd.y, ld.y, c);
        accum_one(h, pd.z, ld.z, c); accum_one(h, pd.w, ld.w, c);
    }
    __syncthreads();

    // u64-paired merge: two packed buckets per atomic (467K atomics total).
    // Fields can't carry across lanes (cnt < 2^20, fg << 2^12 per bucket).
    unsigned long long* __restrict__ g64 =
        (unsigned long long*)(gH + c * NB);
    #pragma unroll
    for (int i = tid; i < NB / 2; i += 256) {        // 1 iter/thread
        const unsigned long long v =
            (unsigned long long)h[2 * i] |
            ((unsigned long long)h[2 * i + 1] << 32);
        if (v) atomicAdd(&g64[i], v);
    }
}

// One block per class. Thread t owns 2 contiguous buckets (descending rank
// order = ascending tid); Hillis-Steele scan over per-thread (n,g) totals,
// then a register-sequential walk with chained fast divides.
// J = 1 - (G-c)/(G+r-c) = r/(G+r-c).
__global__ __launch_bounds__(256) void scan_kernel(
        const unsigned int* __restrict__ gH, unsigned int* __restrict__ acc,
        float* __restrict__ out) {
    const int c = blockIdx.x;
    const int tid = threadIdx.x;
    const unsigned int* __restrict__ g = gH + c * NB;

    unsigned int w[BPT];
    const int base = NB - BPT * (tid + 1);           // thread 0 = top buckets
    unsigned int sumN = 0, sumG = 0;
    #pragma unroll
    for (int j = 0; j < BPT; ++j) {
        w[j] = g[base + j];
        sumN += w[j] & 0xFFFFFu;
        sumG += w[j] >> 20;
    }

    __shared__ unsigned long long sd[256];
    const unsigned long long mine = ((unsigned long long)sumG << 32) | sumN;
    sd[tid] = mine;
    __syncthreads();
    for (int off = 1; off < 256; off <<= 1) {
        unsigned long long add = (tid >= off) ? sd[tid - off] : 0ull;
        __syncthreads();
        sd[tid] += add;
        __syncthreads();
    }
    const unsigned long long incl = sd[tid];
    const unsigned long long tot = sd[255];
    const unsigned long long exc = incl - mine;      // fields don't borrow
    const unsigned int G = (unsigned int)(tot >> 32);

    float accv = 0.0f;
    if (G != 0u) {
        const float Gf = (float)G;
        unsigned int r = (unsigned int)exc;
        unsigned int cf = (unsigned int)(exc >> 32);
        float Jprev = __fdividef((float)r, Gf + (float)r - (float)cf);
        #pragma unroll
        for (int j = BPT - 1; j >= 0; --j) {         // descending error order
            const unsigned int nb = w[j] & 0xFFFFFu;
            const unsigned int gb = w[j] >> 20;
            r += nb; cf += gb;
            if (nb) {
                const float Jnew = __fdividef((float)r, Gf + (float)r - (float)cf);
                const float center = ((float)(base + j) + 0.5f) * (1.0f / (float)NB);
                accv += center * (Jnew - Jprev);
                Jprev = Jnew;
            }
        }
    }

    __shared__ float sf[256];
    sf[tid] = accv;
    __syncthreads();
    for (int off = 128; off > 0; off >>= 1) {
        if (tid < off) sf[tid] += sf[tid + off];
        __syncthreads();
    }
    if (tid == 0) {
        if (G != 0u) {
            atomicAdd((float*)&acc[0], sf[0]);       // class-loss sum
            atomicAdd(&acc[1], 1u);                  // present-class count
        }
        __threadfence();                             // publish before ticket (19 total)
        const unsigned int t = atomicAdd(&acc[2], 1u);
        if (t == NCLS - 1) {                         // last class finalizes
            const float s = atomicAdd((float*)&acc[0], 0.0f);   // coherent read
            const unsigned int k = atomicAdd(&acc[1], 0u);
            out[0] = s / fmaxf((float)k, 1.0f);
        }
    }
}

extern "C" void kernel_launch(void* const* d_in, const int* in_sizes, int n_in,
                              void* d_out, int out_size, void* d_ws, size_t ws_size,
                              hipStream_t stream) {
    const float* input = (const float*)d_in[0];
    const int* target = (const int*)d_in[1];
    float* out = (float*)d_out;

    unsigned int* ws = (unsigned int*)d_ws;
    unsigned int* gH = ws;                    // 38 KB merged packed hist
    unsigned int* acc = gH + GH_WORDS;        // sum(f32), cnt, ticket

    zero_kernel<<<(TOT_WORDS + 255) / 256, 256, 0, stream>>>(ws);
    hist_kernel<<<dim3(NCLS, NCHUNK), 256, 0, stream>>>(input, target, gH);
    scan_kernel<<<NCLS, 256, 0, stream>>>(gH, acc, out);
}

// Round 9
// 98.679 us; speedup vs baseline: 1.1445x; 1.0053x over previous
//
#include <hip/hip_runtime.h>

// Lovasz-Softmax, sort-free (bucket-quantized histogram + Jaccard scan).
// v8: bus-contention model: per-iteration HBM ledger = 268 MB harness poison
// write + 60 MB irreducible read; the poison's L3->HBM drain overlaps hist
// and throttles reads to ~1.2-1.7 TB/s (v6 counters), making hist time
// ~kernel-shape-independent. Only remaining lever: burst efficiency.
// PIXPB 8192->16384: 912 blocks, 64 KB contiguous input stream per block,
// merge-atomic tail halved (~233K u64 atomics). Carried from v7: 4-way
// batched loads (8 x 16B in flight), NB=512, class-fast grid, u64-paired
// merge, ticket-fused finalize in scan. If this is null vs v7 -> drain-bound
// confirmed -> roofline.

#define NCLS   19
#define FHW    393216            // 4*256*384
#define NPIX   786432            // 2*FHW
#define NB     512               // buckets per class (2^9) -> 2 KB LDS
#define PIXPB  16384             // pixels per hist block (64 KB input stream)
#define NCHUNK (NPIX / PIXPB)    // 48 (24 per batch; no batch straddle)
#define BPT    (NB / 256)        // 2 buckets per scan thread

#define GH_WORDS  (NCLS * NB)    // 9728 packed hist words (~38 KB)
#define TOT_WORDS (GH_WORDS + 4) // + acc[4] = sum(f32), cnt, ticket

__device__ __forceinline__ void accum_one(unsigned int* h, float p, int lab, int c) {
    const bool fg = (lab == c);
    const float e = fg ? (1.0f - p) : p;             // e in [0,1]
    unsigned int bits = __float_as_uint(1.0f + e);   // [0x3F800000, 0x40000000]
    unsigned int bkt = (bits - 0x3F800000u) >> 14;   // 9-bit bucket (mantissa-linear)
    bkt = min(bkt, (unsigned int)(NB - 1));          // e == 1.0 exactly
    atomicAdd(&h[bkt], 1u + ((unsigned int)fg << 20)); // packed: cnt | fg<<20
}

__global__ __launch_bounds__(256) void zero_kernel(unsigned int* __restrict__ ws) {
    const int i = blockIdx.x * 256 + threadIdx.x;
    if (i < TOT_WORDS) ws[i] = 0u;                   // gH | acc
}

__global__ __launch_bounds__(256) void hist_kernel(
        const float* __restrict__ input, const int* __restrict__ target,
        unsigned int* __restrict__ gH) {
    __shared__ unsigned int h[NB];                   // 2 KB
    const int tid = threadIdx.x;
    const int c = blockIdx.x;                        // class-fast: neighbors share labels,
    const int chunk = blockIdx.y;                    // merge to different histograms

    #pragma unroll
    for (int i = tid; i < NB; i += 256) h[i] = 0u;
    __syncthreads();

    const int pix0 = chunk * PIXPB;
    const int b = pix0 / FHW;
    const int fhw0 = pix0 % FHW;
    const float4* __restrict__ p4 =
        (const float4*)(input + ((long long)(b * NCLS + c)) * FHW + fhw0);
    const int4* __restrict__ l4 = (const int4*)(target + pix0);

    // 4-way batched loads: 8 independent 16B requests in flight per thread
    // (streams 4 KB apart -> distinct lines/channels), then consume.
    #pragma unroll 2
    for (int i = tid; i < PIXPB / 4; i += 1024) {    // 4 iters/thread
        const float4 pa = p4[i];
        const float4 pb = p4[i + 256];
        const float4 pc = p4[i + 512];
        const float4 pd = p4[i + 768];
        const int4  la = l4[i];
        const int4  lb = l4[i + 256];
        const int4  lc = l4[i + 512];
        const int4  ld = l4[i + 768];
        accum_one(h, pa.x, la.x, c); accum_one(h, pa.y, la.y, c);
        accum_one(h, pa.z, la.z, c); accum_one(h, pa.w, la.w, c);
        accum_one(h, pb.x, lb.x, c); accum_one(h, pb.y, lb.y, c);
        accum_one(h, pb.z, lb.z, c); accum_one(h, pb.w, lb.w, c);
        accum_one(h, pc.x, lc.x, c); accum_one(h, pc.y, lc.y, c);
        accum_one(h, pc.z, lc.z, c); accum_one(h, pc.w, lc.w, c);
        accum_one(h, pd.x, ld.x, c); accum_one(h, pd.y, ld.y, c);
        accum_one(h, pd.z, ld.z, c); accum_one(h, pd.w, ld.w, c);
    }
    __syncthreads();

    // u64-paired merge: two packed buckets per atomic (~233K atomics total).
    // Fields can't carry across lanes (cnt < 2^20, fg << 2^12 per bucket).
    unsigned long long* __restrict__ g64 =
        (unsigned long long*)(gH + c * NB);
    #pragma unroll
    for (int i = tid; i < NB / 2; i += 256) {        // 1 iter/thread
        const unsigned long long v =
            (unsigned long long)h[2 * i] |
            ((unsigned long long)h[2 * i + 1] << 32);
        if (v) atomicAdd(&g64[i], v);
    }
}

// One block per class. Thread t owns 2 contiguous buckets (descending rank
// order = ascending tid); Hillis-Steele scan over per-thread (n,g) totals,
// then a register-sequential walk with chained fast divides.
// J = 1 - (G-c)/(G+r-c) = r/(G+r-c).
__global__ __launch_bounds__(256) void scan_kernel(
        const unsigned int* __restrict__ gH, unsigned int* __restrict__ acc,
        float* __restrict__ out) {
    const int c = blockIdx.x;
    const int tid = threadIdx.x;
    const unsigned int* __restrict__ g = gH + c * NB;

    unsigned int w[BPT];
    const int base = NB - BPT * (tid + 1);           // thread 0 = top buckets
    unsigned int sumN = 0, sumG = 0;
    #pragma unroll
    for (int j = 0; j < BPT; ++j) {
        w[j] = g[base + j];
        sumN += w[j] & 0xFFFFFu;
        sumG += w[j] >> 20;
    }

    __shared__ unsigned long long sd[256];
    const unsigned long long mine = ((unsigned long long)sumG << 32) | sumN;
    sd[tid] = mine;
    __syncthreads();
    for (int off = 1; off < 256; off <<= 1) {
        unsigned long long add = (tid >= off) ? sd[tid - off] : 0ull;
        __syncthreads();
        sd[tid] += add;
        __syncthreads();
    }
    const unsigned long long incl = sd[tid];
    const unsigned long long tot = sd[255];
    const unsigned long long exc = incl - mine;      // fields don't borrow
    const unsigned int G = (unsigned int)(tot >> 32);

    float accv = 0.0f;
    if (G != 0u) {
        const float Gf = (float)G;
        unsigned int r = (unsigned int)exc;
        unsigned int cf = (unsigned int)(exc >> 32);
        float Jprev = __fdividef((float)r, Gf + (float)r - (float)cf);
        #pragma unroll
        for (int j = BPT - 1; j >= 0; --j) {         // descending error order
            const unsigned int nb = w[j] & 0xFFFFFu;
            const unsigned int gb = w[j] >> 20;
            r += nb; cf += gb;
            if (nb) {
                const float Jnew = __fdividef((float)r, Gf + (float)r - (float)cf);
                const float center = ((float)(base + j) + 0.5f) * (1.0f / (float)NB);
                accv += center * (Jnew - Jprev);
                Jprev = Jnew;
            }
        }
    }

    __shared__ float sf[256];
    sf[tid] = accv;
    __syncthreads();
    for (int off = 128; off > 0; off >>= 1) {
        if (tid < off) sf[tid] += sf[tid + off];
        __syncthreads();
    }
    if (tid == 0) {
        if (G != 0u) {
            atomicAdd((float*)&acc[0], sf[0]);       // class-loss sum
            atomicAdd(&acc[1], 1u);                  // present-class count
        }
        __threadfence();                             // publish before ticket (19 total)
        const unsigned int t = atomicAdd(&acc[2], 1u);
        if (t == NCLS - 1) {                         // last class finalizes
            const float s = atomicAdd((float*)&acc[0], 0.0f);   // coherent read
            const unsigned int k = atomicAdd(&acc[1], 0u);
            out[0] = s / fmaxf((float)k, 1.0f);
        }
    }
}

extern "C" void kernel_launch(void* const* d_in, const int* in_sizes, int n_in,
                              void* d_out, int out_size, void* d_ws, size_t ws_size,
                              hipStream_t stream) {
    const float* input = (const float*)d_in[0];
    const int* target = (const int*)d_in[1];
    float* out = (float*)d_out;

    unsigned int* ws = (unsigned int*)d_ws;
    unsigned int* gH = ws;                    // 38 KB merged packed hist
    unsigned int* acc = gH + GH_WORDS;        // sum(f32), cnt, ticket

    zero_kernel<<<(TOT_WORDS + 255) / 256, 256, 0, stream>>>(ws);
    hist_kernel<<<dim3(NCLS, NCHUNK), 256, 0, stream>>>(input, target, gH);
    scan_kernel<<<NCLS, 256, 0, stream>>>(gH, acc, out);
}